// Round 16
// baseline (14692.116 us; speedup 1.0000x reference)
//
#include <hip/hip_runtime.h>

using half8 = __attribute__((ext_vector_type(8))) _Float16;
using f32x4 = __attribute__((ext_vector_type(4))) float;
typedef unsigned long long u64;

static constexpr int TT  = 2048;   // time steps
static constexpr int NB  = 16;     // batch
static constexpr int SS  = 512;    // state dim
static constexpr int NWG = 8;      // WGs per protocol group (64 cols each)
static constexpr int NT  = 2;      // teams (8 batches each)
static constexpr int NBT = 8;      // batches per team
static constexpr int HSLOT = 8;    // hmail ring depth

// -------------------- transpose + fp32->f16 (512x512): out[c][r] = in[r][c] --------------------
__global__ __launch_bounds__(256) void tcvt_kernel(const float* __restrict__ in,
                                                   _Float16* __restrict__ out) {
    __shared__ float tile[32][33];
    int bid = blockIdx.x;
    int rb = (bid >> 4) * 32, cb = (bid & 15) * 32;
    int tx = threadIdx.x & 31, ty = threadIdx.x >> 5;
    for (int rr = ty; rr < 32; rr += 8)
        tile[rr][tx] = in[(size_t)(rb + rr) * SS + cb + tx];
    __syncthreads();
    for (int rr = ty; rr < 32; rr += 8)
        out[(size_t)(cb + rr) * SS + rb + tx] = (_Float16)tile[tx][rr];
}

// -------------------- pack weights for scan: out[kk][c][8] f16 from fp32 [k][c] ----------------
__global__ __launch_bounds__(256) void wpack_kernel(const float* __restrict__ in,
                                                    _Float16* __restrict__ out) {
    int idx = blockIdx.x * blockDim.x + threadIdx.x;   // 64*512 = 32768
    int kk = idx >> 9, c = idx & 511;
    half8 v;
    #pragma unroll
    for (int j = 0; j < 8; ++j) v[j] = (_Float16)in[(size_t)(kk * 8 + j) * SS + c];
    *(half8*)(out + (size_t)idx * 8) = v;
}

// -------------------- W = C0 @ B1 (512x512x512 fp32) --------------------
__global__ __launch_bounds__(256) void wmm_kernel(const float* __restrict__ C0,
                                                  const float* __restrict__ B1,
                                                  float* __restrict__ W) {
    int k = blockIdx.x;
    int tid = threadIdx.x;
    const float* crow = C0 + (size_t)k * SS;
    float s0 = 0.f, s1 = 0.f;
    for (int m = 0; m < SS; ++m) {
        float cv = crow[m];
        s0 += cv * B1[(size_t)m * SS + tid];
        s1 += cv * B1[(size_t)m * SS + tid + 256];
    }
    W[(size_t)k * SS + tid] = s0;
    W[(size_t)k * SS + tid + 256] = s1;
}

// -------------------- zero flags (every launch: graph replay safe) -----------------------------
__global__ __launch_bounds__(512) void zinit_kernel(unsigned* __restrict__ p, int n) {
    int i = blockIdx.x * blockDim.x + threadIdx.x;
    if (i < n) p[i] = 0u;
}

// -------------------- big GEMM: M=32768(b*2048+t), N=512, K=512 --------------------
template <int ALAY, int MODE>
__global__ __launch_bounds__(256) void gemm_kernel(const void* __restrict__ Aptr,
                                                   const _Float16* __restrict__ BT,
                                                   void* __restrict__ Outp) {
    int lane = threadIdx.x & 63;
    int wv   = threadIdx.x >> 6;
    int wid  = blockIdx.x * 4 + wv;
    int mt   = wid >> 3;
    int nb   = (wid & 7) * 64;
    int mbase = mt * 16;
    int lo = lane & 15, q = lane >> 4;

    f32x4 acc[4] = {{0,0,0,0},{0,0,0,0},{0,0,0,0},{0,0,0,0}};

    const float*    Af = (const float*)Aptr;
    const _Float16* Ah = (const _Float16*)Aptr;
    size_t arow = (size_t)(mbase + lo) * SS;

    #pragma unroll 2
    for (int kk = 0; kk < 16; ++kk) {
        int koff = kk * 32 + q * 8;
        half8 af;
        if (ALAY == 0) {
            const float* ar = Af + arow + koff;
            f32x4 a0 = *(const f32x4*)ar;
            f32x4 a1 = *(const f32x4*)(ar + 4);
            #pragma unroll
            for (int j = 0; j < 4; ++j) { af[j] = (_Float16)a0[j]; af[4 + j] = (_Float16)a1[j]; }
        } else {
            af = *(const half8*)(Ah + arow + koff);
        }
        #pragma unroll
        for (int j = 0; j < 4; ++j) {
            int n = nb + j * 16 + lo;
            half8 bf = *(const half8*)(BT + (size_t)n * SS + koff);
            acc[j] = __builtin_amdgcn_mfma_f32_16x16x32_f16(af, bf, acc[j], 0, 0, 0);
        }
    }

    #pragma unroll
    for (int j = 0; j < 4; ++j) {
        #pragma unroll
        for (int i = 0; i < 4; ++i) {
            int m = mbase + q * 4 + i;
            int n = nb + j * 16 + lo;
            if (MODE == 0) {
                ((_Float16*)Outp)[(size_t)m * SS + n] = (_Float16)acc[j][i];
            } else if (MODE == 1) {
                ((float*)Outp)[(size_t)m * SS + n] = acc[j][i];
            } else {
                int t2 = m & (TT - 1);
                int b2 = m >> 11;                 // T = 2048 = 2^11
                ((_Float16*)Outp)[((size_t)t2 * NB + b2) * SS + n] = (_Float16)acc[j][i];
            }
        }
    }
}

// -------------------- fused two-layer pipelined cooperative scan -------------------------------
// = round-15 passing kernel with ONE change: L1's hmail gather of h0(t+1) moves from the step
// tail (where its ~1us LLC round trip was serialized after the GELU) to immediately after B3,
// where it issues back-to-back with the z-gather and stats-gather loads -> all three share one
// LLC RT window; h0 rides in registers through LN/GELU and lands in H0 at the tail (H0 is dead
// after B1; B5 orders the write before next step's MFMA). Certification unchanged: the
// cross-layer poll at step t already requires L0-flag >= t+3, which certifies h0(t+1).
__global__ __launch_bounds__(512) void scan16_kernel(
        const _Float16* __restrict__ U,      // [T][NB][SS] layer-0 input proj
        const _Float16* __restrict__ PA0,    // packed f16 [kk][c][8]
        const _Float16* __restrict__ PK0,
        const float* __restrict__ ab0, const float* __restrict__ gn0, const float* __restrict__ bt0,
        const _Float16* __restrict__ PA1,
        const _Float16* __restrict__ PK1,
        const _Float16* __restrict__ PW,     // packed (C0@B1)
        const float* __restrict__ ab1, const float* __restrict__ gn1, const float* __restrict__ bt1,
        _Float16* __restrict__ hs1,          // [NB][T][SS] layer-1 history out
        u64*      __restrict__ zmail,        // [4 grp][2 par][8 wg][256] u64
        u64*      __restrict__ smail,        // [4 grp][2 par][8 wg][8] u64
        unsigned* __restrict__ flags,        // [4 grp][8 wg][32]
        _Float16* __restrict__ hmail)        // [2 team][8 slot][8 b][512]
{
    const int layer = blockIdx.x >> 4;
    const int team  = (blockIdx.x >> 3) & 1;
    const int wg    = blockIdx.x & 7;
    const int btm   = team * NBT;
    const int tid   = threadIdx.x;
    const int wv    = tid >> 6;
    const int lane  = tid & 63;
    const int q     = lane >> 4;
    const int r     = lane & 15;

    const _Float16* PA  = layer ? PA1 : PA0;
    const _Float16* PK  = layer ? PK1 : PK0;
    const float*    abp = layer ? ab1 : ab0;
    const float*    gnp = layer ? gn1 : gn0;
    const float*    btp = layer ? bt1 : bt0;

    const int pg = layer * 2 + team;
    u64*      zmailT = zmail + (size_t)pg * (2 * NWG * 256);
    u64*      smailT = smail + (size_t)pg * (2 * NWG * 8);
    unsigned* flagsT = flags + (size_t)pg * (NWG * 32);
    unsigned* flagsO = flags + (size_t)((1 - layer) * 2 + team) * (NWG * 32);
    _Float16* hmailT = hmail + (size_t)team * (HSLOT * NBT * SS);

    __shared__ _Float16 H16[16][520];          // own-layer h (rows 8-15 stay zero)
    __shared__ _Float16 H0[16][520];           // layer-0 h staged for L1 (rows 8-15 zero)
    alignas(16) __shared__ float ZW32[8][64];
    __shared__ float STAT[4][16][2];
    __shared__ float GG[512], BB[512];

    const int ub = tid & 7;             // batch within team
    const int ug = tid >> 3;            // 0..63
    const int uc = ug * 8;              // col start (8 cols/thread)
    const int ow = ug >> 3;             // owning WG of this col slice

    for (int e = tid; e < 16 * 520; e += 512) {
        (&H16[0][0])[e] = (_Float16)0.f;
        (&H0[0][0])[e]  = (_Float16)0.f;
    }
    GG[tid] = gnp[tid];
    BB[tid] = btp[tid];

    const bool mf = (wv < 4);
    const int ccol = wg * 64 + (wv & 3) * 16 + r;
    const float abreg = abp[ccol];

    float hreg[8];
    #pragma unroll
    for (int i = 0; i < 8; ++i) hreg[i] = 0.f;
    float uprev[4] = {0.f, 0.f, 0.f, 0.f};
    float ucur[4]  = {0.f, 0.f, 0.f, 0.f};
    if (layer == 0 && mf && q < 2) {
        #pragma unroll
        for (int i = 0; i < 4; ++i)
            ucur[i] = (float)U[(size_t)(btm + q * 4 + i) * SS + ccol];   // t = 0
    }
    __syncthreads();

    // L1 prologue: wait for h0(0) (certified by L0 flag >= 2), stage into H0
    if (layer == 1) {
        if (wv == 0 && lane < 8) {
            while (__hip_atomic_load(&flagsO[lane * 32], __ATOMIC_RELAXED,
                                     __HIP_MEMORY_SCOPE_AGENT) < 2u) {}
        }
        __syncthreads();
        {
            const u64* hp = (const u64*)(hmailT + ((size_t)0 * NBT + ub) * SS + uc);
            union { u64 u[2]; half8 h; } hv;
            hv.u[0] = __hip_atomic_load(hp + 0, __ATOMIC_RELAXED, __HIP_MEMORY_SCOPE_AGENT);
            hv.u[1] = __hip_atomic_load(hp + 1, __ATOMIC_RELAXED, __HIP_MEMORY_SCOPE_AGENT);
            *(half8*)&H0[ub][uc] = hv.h;
        }
        __syncthreads();
    }

    for (int t = 0; t < TT; ++t) {
        const int par = t & 1;

        if (mf) {
            f32x4 zA = {0.f, 0.f, 0.f, 0.f}, zK = {0.f, 0.f, 0.f, 0.f};
            #pragma unroll
            for (int ks = 0; ks < 16; ++ks) {
                half8 hf = *(const half8*)(&H16[r][ks * 32 + q * 8]);
                half8 wa = *(const half8*)(PA + (((size_t)(ks * 4 + q)) * SS + ccol) * 8);
                half8 wk = *(const half8*)(PK + (((size_t)(ks * 4 + q)) * SS + ccol) * 8);
                zA = __builtin_amdgcn_mfma_f32_16x16x32_f16(hf, wa, zA, 0, 0, 0);
                zK = __builtin_amdgcn_mfma_f32_16x16x32_f16(hf, wk, zK, 0, 0, 0);
            }
            if (layer == 1) {          // U1(t) = h0(t) @ W, same fragment pattern (fp32 result)
                f32x4 ua = {0.f, 0.f, 0.f, 0.f};
                #pragma unroll
                for (int ks = 0; ks < 16; ++ks) {
                    half8 h0f = *(const half8*)(&H0[r][ks * 32 + q * 8]);
                    half8 ww  = *(const half8*)(PW + (((size_t)(ks * 4 + q)) * SS + ccol) * 8);
                    ua = __builtin_amdgcn_mfma_f32_16x16x32_f16(h0f, ww, ua, 0, 0, 0);
                }
                #pragma unroll
                for (int i = 0; i < 4; ++i) ucur[i] = ua[i];
            }

            float z[4];
            #pragma unroll
            for (int i = 0; i < 4; ++i) {
                z[i] = zA[i] + ucur[i] + abreg + zK[i] * uprev[i];
                uprev[i] = ucur[i];
            }
            if (q < 2) {
                #pragma unroll
                for (int i = 0; i < 4; ++i)
                    ZW32[q * 4 + i][(wv & 3) * 16 + r] = z[i];
            }

            float s1[4], s2[4];
            #pragma unroll
            for (int i = 0; i < 4; ++i) { s1[i] = z[i]; s2[i] = z[i] * z[i]; }
            #pragma unroll
            for (int off = 1; off < 16; off <<= 1) {
                #pragma unroll
                for (int i = 0; i < 4; ++i) {
                    s1[i] += __shfl_xor(s1[i], off, 64);
                    s2[i] += __shfl_xor(s2[i], off, 64);
                }
            }
            if (r == 0) {
                #pragma unroll
                for (int i = 0; i < 4; ++i) {
                    STAT[wv][q * 4 + i][0] = s1[i];
                    STAT[wv][q * 4 + i][1] = s2[i];
                }
            }
        }
        __syncthreads();                                   // B1

        if (tid < 256) {
            u64 v = ((const u64*)ZW32)[tid];
            __hip_atomic_store(&zmailT[((size_t)par * NWG + wg) * 256 + tid], v,
                               __ATOMIC_RELAXED, __HIP_MEMORY_SCOPE_AGENT);
        }
        if (wv == 0 && lane < NBT) {
            float S1 = STAT[0][lane][0] + STAT[1][lane][0] + STAT[2][lane][0] + STAT[3][lane][0];
            float S2 = STAT[0][lane][1] + STAT[1][lane][1] + STAT[2][lane][1] + STAT[3][lane][1];
            union { float f[2]; u64 u; } pk;
            pk.f[0] = S1; pk.f[1] = S2;
            __hip_atomic_store(&smailT[((size_t)par * NWG + wg) * 8 + lane], pk.u,
                               __ATOMIC_RELAXED, __HIP_MEMORY_SCOPE_AGENT);
        }
        if (layer == 0 && mf && q < 2) {        // prefetch next-step U under the drain
            const int tn = (t + 1 < TT) ? (t + 1) : t;
            #pragma unroll
            for (int i = 0; i < 4; ++i)
                ucur[i] = (float)U[((size_t)tn * NB + btm + q * 4 + i) * SS + ccol];
        }
        __builtin_amdgcn_s_waitcnt(0);
        __syncthreads();                                   // B2: z (+ prev h) at coherence point

        if (tid == 0)
            __hip_atomic_store(&flagsT[wg * 32], (unsigned)(t + 1),
                               __ATOMIC_RELAXED, __HIP_MEMORY_SCOPE_AGENT);
        if (wv == 0 && lane >= 1 && lane < NWG) {          // own peers
            unsigned* fp = &flagsT[((wg + lane) & (NWG - 1)) * 32];
            while (__hip_atomic_load(fp, __ATOMIC_RELAXED, __HIP_MEMORY_SCOPE_AGENT)
                   < (unsigned)(t + 1)) {}
        }
        if (wv == 0 && lane >= 8 && lane < 16) {           // cross-layer
            unsigned thr;
            if (layer == 0) thr = (t > 7) ? (unsigned)(t - 7) : 0u;      // hmail ring guard
            else            thr = (t + 1 < TT) ? (unsigned)(t + 3) : 0u; // h0(t+1) certified
            if (thr) {
                unsigned* fp = &flagsO[(lane - 8) * 32];
                while (__hip_atomic_load(fp, __ATOMIC_RELAXED, __HIP_MEMORY_SCOPE_AGENT) < thr) {}
            }
        }
        __syncthreads();                                   // B3

        // L1: issue hmail gather of h0(t+1) EARLY -- shares the LLC RT window with the z/stats
        // gathers below (certified by the cross-layer poll above; H0 is dead after B1)
        u64 h0u0 = 0, h0u1 = 0;
        if (layer == 1 && t + 1 < TT) {
            const u64* hp = (const u64*)(hmailT
                            + (((size_t)((t + 1) & (HSLOT - 1))) * NBT + ub) * SS + uc);
            h0u0 = __hip_atomic_load(hp + 0, __ATOMIC_RELAXED, __HIP_MEMORY_SCOPE_AGENT);
            h0u1 = __hip_atomic_load(hp + 1, __ATOMIC_RELAXED, __HIP_MEMORY_SCOPE_AGENT);
        }

        // gather z (batch ub, cols uc..uc+7)
        float zz[8];
        if (ow == wg) {
            #pragma unroll
            for (int i = 0; i < 8; ++i) zz[i] = ZW32[ub][(uc & 63) + i];
        } else {
            union { u64 u[4]; float f[8]; } zu;
            const u64* src = &zmailT[((size_t)par * NWG + ow) * 256 + ub * 32 + ((uc & 63) >> 1)];
            #pragma unroll
            for (int i = 0; i < 4; ++i)
                zu.u[i] = __hip_atomic_load(src + i, __ATOMIC_RELAXED, __HIP_MEMORY_SCOPE_AGENT);
            #pragma unroll
            for (int i = 0; i < 8; ++i) zz[i] = zu.f[i];
        }
        // global LN stats (fixed ascending WG order -> identical bits in every WG)
        float S1 = 0.f, S2 = 0.f;
        #pragma unroll
        for (int i = 0; i < NWG; ++i) {
            union { u64 u; float f[2]; } pk;
            pk.u = __hip_atomic_load(&smailT[((size_t)par * NWG + i) * 8 + ub],
                                     __ATOMIC_RELAXED, __HIP_MEMORY_SCOPE_AGENT);
            S1 += pk.f[0]; S2 += pk.f[1];
        }
        const float mu  = S1 * (1.0f / SS);
        const float var = S2 * (1.0f / SS) - mu * mu;
        const float rs  = rsqrtf(var + 1e-5f);

        // replicated LN + exact GELU + h update (8 elems/thread)
        half8 hh;
        #pragma unroll
        for (int i4 = 0; i4 < 2; ++i4) {
            f32x4 gq = *(const f32x4*)&GG[uc + i4 * 4];
            f32x4 bq = *(const f32x4*)&BB[uc + i4 * 4];
            #pragma unroll
            for (int jj = 0; jj < 4; ++jj) {
                const int e = i4 * 4 + jj;
                float zn = (zz[e] - mu) * rs * gq[jj] + bq[jj];
                float ge = 0.5f * zn * (1.0f + erff(zn * 0.70710678118654752f));
                hreg[e] += ge;
                hh[e] = (_Float16)hreg[e];
            }
        }
        *(half8*)(&H16[ub][uc]) = hh;

        if (layer == 0) {
            if (ow == wg) {                                // publish h(t) into hmail ring
                u64* hp = (u64*)(hmailT + (((size_t)(t & (HSLOT - 1))) * NBT + ub) * SS + uc);
                union { half8 h; u64 u[2]; } hv; hv.h = hh;
                __hip_atomic_store(hp + 0, hv.u[0], __ATOMIC_RELAXED, __HIP_MEMORY_SCOPE_AGENT);
                __hip_atomic_store(hp + 1, hv.u[1], __ATOMIC_RELAXED, __HIP_MEMORY_SCOPE_AGENT);
            }
        } else {
            if (ow == wg)                                  // history out (feeds final GEMM)
                *(half8*)(hs1 + ((size_t)(btm + ub) * TT + t) * SS + uc) = hh;
            if (t + 1 < TT) {                              // land pre-gathered h0(t+1) in H0
                union { u64 u[2]; half8 h; } hv;
                hv.u[0] = h0u0; hv.u[1] = h0u1;
                *(half8*)&H0[ub][uc] = hv.h;
            }
        }
        __syncthreads();                                   // B5
    }

    // L0 epilogue: certify the last hmail writes (h0(TT-1)) with a final flag
    if (layer == 0) {
        __builtin_amdgcn_s_waitcnt(0);
        __syncthreads();
        if (tid == 0)
            __hip_atomic_store(&flagsT[wg * 32], (unsigned)(TT + 1),
                               __ATOMIC_RELAXED, __HIP_MEMORY_SCOPE_AGENT);
    }
}

// -------------------- host launch --------------------
extern "C" void kernel_launch(void* const* d_in, const int* in_sizes, int n_in,
                              void* d_out, int out_size, void* d_ws, size_t ws_size,
                              hipStream_t stream) {
    const float* x   = (const float*)d_in[0];
    const float* A0  = (const float*)d_in[1];
    const float* B0  = (const float*)d_in[2];
    const float* C0  = (const float*)d_in[3];
    const float* K0  = (const float*)d_in[4];
    const float* ab0 = (const float*)d_in[5];
    const float* g0  = (const float*)d_in[6];
    const float* bt0 = (const float*)d_in[7];
    const float* A1  = (const float*)d_in[8];
    const float* B1  = (const float*)d_in[9];
    const float* C1  = (const float*)d_in[10];
    const float* K1  = (const float*)d_in[11];
    const float* ab1 = (const float*)d_in[12];
    const float* g1  = (const float*)d_in[13];
    const float* bt1 = (const float*)d_in[14];

    char* ws = (char*)d_ws;
    size_t off = 0;
    auto alloc = [&](size_t bytes) { size_t o = off; off = (off + bytes + 255) & ~(size_t)255; return o; };

    const size_t BUF_BYTES = (size_t)NB * TT * SS * 2;   // 33.5 MB f16
    const size_t WP_BYTES  = (size_t)SS * SS * 2;        // 512 KB f16

    _Float16* U0  = (_Float16*)(ws + alloc(BUF_BYTES));  // [t][b][c]
    _Float16* hs1 = (_Float16*)(ws + alloc(BUF_BYTES));  // [b][t][c]
    _Float16* B0T = (_Float16*)(ws + alloc(WP_BYTES));
    _Float16* C1T = (_Float16*)(ws + alloc(WP_BYTES));
    _Float16* PA0 = (_Float16*)(ws + alloc(WP_BYTES));   // packed [kk][c][8]
    _Float16* PK0 = (_Float16*)(ws + alloc(WP_BYTES));
    _Float16* PA1 = (_Float16*)(ws + alloc(WP_BYTES));
    _Float16* PK1 = (_Float16*)(ws + alloc(WP_BYTES));
    _Float16* PW  = (_Float16*)(ws + alloc(WP_BYTES));
    float*    Wf  = (float*)(ws + alloc((size_t)SS * SS * 4));
    u64*      zmail = (u64*)(ws + alloc((size_t)4 * 2 * NWG * 256 * 8));   // 128 KB
    u64*      smail = (u64*)(ws + alloc((size_t)4 * 2 * NWG * 8 * 8));     // 4 KB
    unsigned* flags = (unsigned*)(ws + alloc((size_t)4 * NWG * 32 * 4));   // 4 KB
    _Float16* hmail = (_Float16*)(ws + alloc((size_t)NT * HSLOT * NBT * SS * 2)); // 128 KB

    // zero flags (stream-ordered; graph-replay safe)
    zinit_kernel<<<2, 512, 0, stream>>>(flags, 4 * NWG * 32);

    // weight preps
    tcvt_kernel<<<256, 256, 0, stream>>>(B0, B0T);
    tcvt_kernel<<<256, 256, 0, stream>>>(C1, C1T);
    wmm_kernel<<<512, 256, 0, stream>>>(C0, B1, Wf);     // W = C0 @ B1 (layer-fold)
    wpack_kernel<<<128, 256, 0, stream>>>(A0, PA0);
    wpack_kernel<<<128, 256, 0, stream>>>(K0, PK0);
    wpack_kernel<<<128, 256, 0, stream>>>(A1, PA1);
    wpack_kernel<<<128, 256, 0, stream>>>(K1, PK1);
    wpack_kernel<<<128, 256, 0, stream>>>(Wf, PW);

    // U0 = x @ B0, scan layout [t][b][c]
    gemm_kernel<0, 2><<<4096, 256, 0, stream>>>((const void*)x, B0T, (void*)U0);

    // fused two-layer pipelined scan: 32 WGs = {L0,L1} x {team0,team1} x 8
    scan16_kernel<<<32, 512, 0, stream>>>(U0, PA0, PK0, ab0, g0, bt0,
                                          PA1, PK1, PW, ab1, g1, bt1,
                                          hs1, zmail, smail, flags, hmail);

    // out = hs1 @ C1 (fp32 [b][t][c])
    gemm_kernel<1, 1><<<4096, 256, 0, stream>>>((const void*)hs1, C1T, d_out);
}

// Round 18
// 13978.728 us; speedup vs baseline: 1.0510x; 1.0510x over previous
//
#include <hip/hip_runtime.h>

using half8 = __attribute__((ext_vector_type(8))) _Float16;
using f32x4 = __attribute__((ext_vector_type(4))) float;
typedef unsigned long long u64;

static constexpr int TT  = 2048;   // time steps
static constexpr int NB  = 16;     // batch
static constexpr int SS  = 512;    // state dim
static constexpr int NWG = 8;      // WGs per protocol group (64 cols each)
static constexpr int NT  = 2;      // teams (8 batches each)
static constexpr int NBT = 8;      // batches per team
static constexpr int HSLOT = 8;    // u1mail ring depth
static constexpr int U1SLOT = NWG * 4 * 2 * 16 * 2;   // 2048 u64 per team-slot

// -------------------- transpose + fp32->f16 (512x512): out[c][r] = in[r][c] --------------------
__global__ __launch_bounds__(256) void tcvt_kernel(const float* __restrict__ in,
                                                   _Float16* __restrict__ out) {
    __shared__ float tile[32][33];
    int bid = blockIdx.x;
    int rb = (bid >> 4) * 32, cb = (bid & 15) * 32;
    int tx = threadIdx.x & 31, ty = threadIdx.x >> 5;
    for (int rr = ty; rr < 32; rr += 8)
        tile[rr][tx] = in[(size_t)(rb + rr) * SS + cb + tx];
    __syncthreads();
    for (int rr = ty; rr < 32; rr += 8)
        out[(size_t)(cb + rr) * SS + rb + tx] = (_Float16)tile[tx][rr];
}

// -------------------- pack weights for scan: out[kk][c][8] f16 from fp32 [k][c] ----------------
__global__ __launch_bounds__(256) void wpack_kernel(const float* __restrict__ in,
                                                    _Float16* __restrict__ out) {
    int idx = blockIdx.x * blockDim.x + threadIdx.x;   // 64*512 = 32768
    int kk = idx >> 9, c = idx & 511;
    half8 v;
    #pragma unroll
    for (int j = 0; j < 8; ++j) v[j] = (_Float16)in[(size_t)(kk * 8 + j) * SS + c];
    *(half8*)(out + (size_t)idx * 8) = v;
}

// -------------------- W = C0 @ B1 (512x512x512 fp32) --------------------
__global__ __launch_bounds__(256) void wmm_kernel(const float* __restrict__ C0,
                                                  const float* __restrict__ B1,
                                                  float* __restrict__ W) {
    int k = blockIdx.x;
    int tid = threadIdx.x;
    const float* crow = C0 + (size_t)k * SS;
    float s0 = 0.f, s1 = 0.f;
    for (int m = 0; m < SS; ++m) {
        float cv = crow[m];
        s0 += cv * B1[(size_t)m * SS + tid];
        s1 += cv * B1[(size_t)m * SS + tid + 256];
    }
    W[(size_t)k * SS + tid] = s0;
    W[(size_t)k * SS + tid + 256] = s1;
}

// -------------------- zero flags (every launch: graph replay safe) -----------------------------
__global__ __launch_bounds__(512) void zinit_kernel(unsigned* __restrict__ p, int n) {
    int i = blockIdx.x * blockDim.x + threadIdx.x;
    if (i < n) p[i] = 0u;
}

// -------------------- big GEMM: M=32768(b*2048+t), N=512, K=512 --------------------
template <int ALAY, int MODE>
__global__ __launch_bounds__(256) void gemm_kernel(const void* __restrict__ Aptr,
                                                   const _Float16* __restrict__ BT,
                                                   void* __restrict__ Outp) {
    int lane = threadIdx.x & 63;
    int wv   = threadIdx.x >> 6;
    int wid  = blockIdx.x * 4 + wv;
    int mt   = wid >> 3;
    int nb   = (wid & 7) * 64;
    int mbase = mt * 16;
    int lo = lane & 15, q = lane >> 4;

    f32x4 acc[4] = {{0,0,0,0},{0,0,0,0},{0,0,0,0},{0,0,0,0}};

    const float*    Af = (const float*)Aptr;
    const _Float16* Ah = (const _Float16*)Aptr;
    size_t arow = (size_t)(mbase + lo) * SS;

    #pragma unroll 2
    for (int kk = 0; kk < 16; ++kk) {
        int koff = kk * 32 + q * 8;
        half8 af;
        if (ALAY == 0) {
            const float* ar = Af + arow + koff;
            f32x4 a0 = *(const f32x4*)ar;
            f32x4 a1 = *(const f32x4*)(ar + 4);
            #pragma unroll
            for (int j = 0; j < 4; ++j) { af[j] = (_Float16)a0[j]; af[4 + j] = (_Float16)a1[j]; }
        } else {
            af = *(const half8*)(Ah + arow + koff);
        }
        #pragma unroll
        for (int j = 0; j < 4; ++j) {
            int n = nb + j * 16 + lo;
            half8 bf = *(const half8*)(BT + (size_t)n * SS + koff);
            acc[j] = __builtin_amdgcn_mfma_f32_16x16x32_f16(af, bf, acc[j], 0, 0, 0);
        }
    }

    #pragma unroll
    for (int j = 0; j < 4; ++j) {
        #pragma unroll
        for (int i = 0; i < 4; ++i) {
            int m = mbase + q * 4 + i;
            int n = nb + j * 16 + lo;
            if (MODE == 0) {
                ((_Float16*)Outp)[(size_t)m * SS + n] = (_Float16)acc[j][i];
            } else if (MODE == 1) {
                ((float*)Outp)[(size_t)m * SS + n] = acc[j][i];
            } else {
                int t2 = m & (TT - 1);
                int b2 = m >> 11;                 // T = 2048 = 2^11
                ((_Float16*)Outp)[((size_t)t2 * NB + b2) * SS + n] = (_Float16)acc[j][i];
            }
        }
    }
}

// -------------------- fused two-layer pipelined cooperative scan (balanced) --------------------
// Change vs round-16: the U1 = h0 @ W matmul moves from L1 into L0. At L0's step t, H16 already
// holds h(t-1) (read anyway for zA/zK), so U1(t-1) costs 16 MFMAs on the same fragments + the W
// stream. L0 publishes the fp32 results into u1mail indexed by the consumer's own
// (wg, wv&3, q, r) coordinates -> L1 gathers 2 u64 straight into its ucur registers: no H0 LDS,
// no hmail, no W stream, no extra MFMAs on L1. Certification thresholds are UNCHANGED:
// U1(t+1) is computed at L0 step t+2, drained at its B2, certified by flag t+3 = the existing
// cross-layer poll. Ring guard: L0 step t's publish destroys U1(t-9); the guard from step t-1
// gives L1-flag >= t-8 >= t-9 (safe). Epilogue computes U1(TT-1) from the final H16, publishes,
// drains, then flag TT+1 (matches L1's final threshold t+3 = TT+1 at t = TT-2).
// Numerics bit-identical to round 15/16 (same f16 bits into the same MFMA).
__global__ __launch_bounds__(512) void scan17_kernel(
        const _Float16* __restrict__ U,      // [T][NB][SS] layer-0 input proj
        const _Float16* __restrict__ PA0,    // packed f16 [kk][c][8]
        const _Float16* __restrict__ PK0,
        const float* __restrict__ ab0, const float* __restrict__ gn0, const float* __restrict__ bt0,
        const _Float16* __restrict__ PA1,
        const _Float16* __restrict__ PK1,
        const _Float16* __restrict__ PW,     // packed (C0@B1)
        const float* __restrict__ ab1, const float* __restrict__ gn1, const float* __restrict__ bt1,
        _Float16* __restrict__ hs1,          // [NB][T][SS] layer-1 history out
        u64*      __restrict__ zmail,        // [4 grp][2 par][8 wg][256] u64
        u64*      __restrict__ smail,        // [4 grp][2 par][8 wg][8] u64
        unsigned* __restrict__ flags,        // [4 grp][8 wg][32]
        u64*      __restrict__ u1mail)       // [2 team][8 slot][8 wg][4 wv][2 q][16 r][2] u64
{
    const int layer = blockIdx.x >> 4;
    const int team  = (blockIdx.x >> 3) & 1;
    const int wg    = blockIdx.x & 7;
    const int btm   = team * NBT;
    const int tid   = threadIdx.x;
    const int wv    = tid >> 6;
    const int lane  = tid & 63;
    const int q     = lane >> 4;
    const int r     = lane & 15;

    const _Float16* PA  = layer ? PA1 : PA0;
    const _Float16* PK  = layer ? PK1 : PK0;
    const float*    abp = layer ? ab1 : ab0;
    const float*    gnp = layer ? gn1 : gn0;
    const float*    btp = layer ? bt1 : bt0;

    const int pg = layer * 2 + team;
    u64*      zmailT  = zmail + (size_t)pg * (2 * NWG * 256);
    u64*      smailT  = smail + (size_t)pg * (2 * NWG * 8);
    unsigned* flagsT  = flags + (size_t)pg * (NWG * 32);
    unsigned* flagsO  = flags + (size_t)((1 - layer) * 2 + team) * (NWG * 32);
    u64*      u1mailT = u1mail + (size_t)team * HSLOT * U1SLOT;

    __shared__ _Float16 H16[16][520];          // own-layer h (rows 8-15 stay zero)
    alignas(16) __shared__ float ZW32[8][64];
    __shared__ float STAT[4][16][2];
    __shared__ float GG[512], BB[512];

    const int ub = tid & 7;             // batch within team
    const int ug = tid >> 3;            // 0..63
    const int uc = ug * 8;              // col start (8 cols/thread)
    const int ow = ug >> 3;             // owning WG of this col slice

    for (int e = tid; e < 16 * 520; e += 512) (&H16[0][0])[e] = (_Float16)0.f;
    GG[tid] = gnp[tid];
    BB[tid] = btp[tid];

    const bool mf = (wv < 4);
    const int ccol = wg * 64 + (wv & 3) * 16 + r;
    const float abreg = abp[ccol];

    // u1mail address for THIS thread's (wg, wv&3, q, r) -- producer and consumer coincide
    auto u1addr = [&](int slot) -> u64* {
        return u1mailT + ((((size_t)slot * NWG + wg) * 4 + (wv & 3)) * 2 + q) * 32 + r * 2;
    };

    float hreg[8];
    #pragma unroll
    for (int i = 0; i < 8; ++i) hreg[i] = 0.f;
    float uprev[4] = {0.f, 0.f, 0.f, 0.f};
    float ucur[4]  = {0.f, 0.f, 0.f, 0.f};
    float unext[4] = {0.f, 0.f, 0.f, 0.f};
    float uapub[4] = {0.f, 0.f, 0.f, 0.f};
    if (layer == 0 && mf && q < 2) {
        #pragma unroll
        for (int i = 0; i < 4; ++i)
            ucur[i] = (float)U[(size_t)(btm + q * 4 + i) * SS + ccol];   // t = 0
    }
    __syncthreads();

    // L1 prologue: wait for U1(0) (computed at L0 step 1, certified by flag >= 2), gather to regs
    if (layer == 1) {
        if (wv == 0 && lane < 8) {
            while (__hip_atomic_load(&flagsO[lane * 32], __ATOMIC_RELAXED,
                                     __HIP_MEMORY_SCOPE_AGENT) < 2u) {}
        }
        __syncthreads();
        if (mf && q < 2) {
            const u64* up = u1addr(0);
            union { u64 u; float f[2]; } a, b;
            a.u = __hip_atomic_load(up + 0, __ATOMIC_RELAXED, __HIP_MEMORY_SCOPE_AGENT);
            b.u = __hip_atomic_load(up + 1, __ATOMIC_RELAXED, __HIP_MEMORY_SCOPE_AGENT);
            unext[0] = a.f[0]; unext[1] = a.f[1]; unext[2] = b.f[0]; unext[3] = b.f[1];
        }
    }

    for (int t = 0; t < TT; ++t) {
        const int par = t & 1;

        if (mf) {
            if (layer == 1) {
                #pragma unroll
                for (int i = 0; i < 4; ++i) ucur[i] = unext[i];
            }
            f32x4 zA = {0.f, 0.f, 0.f, 0.f}, zK = {0.f, 0.f, 0.f, 0.f};
            #pragma unroll
            for (int ks = 0; ks < 16; ++ks) {
                half8 hf = *(const half8*)(&H16[r][ks * 32 + q * 8]);
                half8 wa = *(const half8*)(PA + (((size_t)(ks * 4 + q)) * SS + ccol) * 8);
                half8 wk = *(const half8*)(PK + (((size_t)(ks * 4 + q)) * SS + ccol) * 8);
                zA = __builtin_amdgcn_mfma_f32_16x16x32_f16(hf, wa, zA, 0, 0, 0);
                zK = __builtin_amdgcn_mfma_f32_16x16x32_f16(hf, wk, zK, 0, 0, 0);
            }
            if (layer == 0) {          // U1(t-1) = h(t-1) @ W on the SAME H16 fragments
                f32x4 ua = {0.f, 0.f, 0.f, 0.f};
                #pragma unroll
                for (int ks = 0; ks < 16; ++ks) {
                    half8 hf = *(const half8*)(&H16[r][ks * 32 + q * 8]);
                    half8 ww = *(const half8*)(PW + (((size_t)(ks * 4 + q)) * SS + ccol) * 8);
                    ua = __builtin_amdgcn_mfma_f32_16x16x32_f16(hf, ww, ua, 0, 0, 0);
                }
                #pragma unroll
                for (int i = 0; i < 4; ++i) uapub[i] = ua[i];
            }

            float z[4];
            #pragma unroll
            for (int i = 0; i < 4; ++i) {
                z[i] = zA[i] + ucur[i] + abreg + zK[i] * uprev[i];
                uprev[i] = ucur[i];
            }
            if (q < 2) {
                #pragma unroll
                for (int i = 0; i < 4; ++i)
                    ZW32[q * 4 + i][(wv & 3) * 16 + r] = z[i];
            }

            float s1[4], s2[4];
            #pragma unroll
            for (int i = 0; i < 4; ++i) { s1[i] = z[i]; s2[i] = z[i] * z[i]; }
            #pragma unroll
            for (int off = 1; off < 16; off <<= 1) {
                #pragma unroll
                for (int i = 0; i < 4; ++i) {
                    s1[i] += __shfl_xor(s1[i], off, 64);
                    s2[i] += __shfl_xor(s2[i], off, 64);
                }
            }
            if (r == 0) {
                #pragma unroll
                for (int i = 0; i < 4; ++i) {
                    STAT[wv][q * 4 + i][0] = s1[i];
                    STAT[wv][q * 4 + i][1] = s2[i];
                }
            }
        }
        __syncthreads();                                   // B1

        if (tid < 256) {
            u64 v = ((const u64*)ZW32)[tid];
            __hip_atomic_store(&zmailT[((size_t)par * NWG + wg) * 256 + tid], v,
                               __ATOMIC_RELAXED, __HIP_MEMORY_SCOPE_AGENT);
        }
        if (wv == 0 && lane < NBT) {
            float S1 = STAT[0][lane][0] + STAT[1][lane][0] + STAT[2][lane][0] + STAT[3][lane][0];
            float S2 = STAT[0][lane][1] + STAT[1][lane][1] + STAT[2][lane][1] + STAT[3][lane][1];
            union { float f[2]; u64 u; } pk;
            pk.f[0] = S1; pk.f[1] = S2;
            __hip_atomic_store(&smailT[((size_t)par * NWG + wg) * 8 + lane], pk.u,
                               __ATOMIC_RELAXED, __HIP_MEMORY_SCOPE_AGENT);
        }
        if (layer == 0 && mf && q < 2) {
            // publish U1(t-1) (slot write is ring-guard-safe: guard from step t-1 covers it)
            u64* up = u1addr((t - 1) & (HSLOT - 1));
            union { float f[2]; u64 u; } p0, p1;
            p0.f[0] = uapub[0]; p0.f[1] = uapub[1];
            p1.f[0] = uapub[2]; p1.f[1] = uapub[3];
            __hip_atomic_store(up + 0, p0.u, __ATOMIC_RELAXED, __HIP_MEMORY_SCOPE_AGENT);
            __hip_atomic_store(up + 1, p1.u, __ATOMIC_RELAXED, __HIP_MEMORY_SCOPE_AGENT);
            // prefetch next-step U under the drain
            const int tn = (t + 1 < TT) ? (t + 1) : t;
            #pragma unroll
            for (int i = 0; i < 4; ++i)
                ucur[i] = (float)U[((size_t)tn * NB + btm + q * 4 + i) * SS + ccol];
        }
        __builtin_amdgcn_s_waitcnt(0);
        __syncthreads();                                   // B2: z + U1 at coherence point

        if (tid == 0)
            __hip_atomic_store(&flagsT[wg * 32], (unsigned)(t + 1),
                               __ATOMIC_RELAXED, __HIP_MEMORY_SCOPE_AGENT);
        if (wv == 0 && lane >= 1 && lane < NWG) {          // own peers
            unsigned* fp = &flagsT[((wg + lane) & (NWG - 1)) * 32];
            while (__hip_atomic_load(fp, __ATOMIC_RELAXED, __HIP_MEMORY_SCOPE_AGENT)
                   < (unsigned)(t + 1)) {}
        }
        if (wv == 0 && lane >= 8 && lane < 16) {           // cross-layer
            unsigned thr;
            if (layer == 0) thr = (t > 7) ? (unsigned)(t - 7) : 0u;      // ring overwrite guard
            else            thr = (t + 1 < TT) ? (unsigned)(t + 3) : 0u; // U1(t+1) certified
            if (thr) {
                unsigned* fp = &flagsO[(lane - 8) * 32];
                while (__hip_atomic_load(fp, __ATOMIC_RELAXED, __HIP_MEMORY_SCOPE_AGENT) < thr) {}
            }
        }
        __syncthreads();                                   // B3

        // L1: gather U1(t+1) straight into registers (shares the RT window with z/stats gathers)
        if (layer == 1 && mf && q < 2 && t + 1 < TT) {
            const u64* up = u1addr((t + 1) & (HSLOT - 1));
            union { u64 u; float f[2]; } a, b;
            a.u = __hip_atomic_load(up + 0, __ATOMIC_RELAXED, __HIP_MEMORY_SCOPE_AGENT);
            b.u = __hip_atomic_load(up + 1, __ATOMIC_RELAXED, __HIP_MEMORY_SCOPE_AGENT);
            unext[0] = a.f[0]; unext[1] = a.f[1]; unext[2] = b.f[0]; unext[3] = b.f[1];
        }

        // gather z (batch ub, cols uc..uc+7)
        float zz[8];
        if (ow == wg) {
            #pragma unroll
            for (int i = 0; i < 8; ++i) zz[i] = ZW32[ub][(uc & 63) + i];
        } else {
            union { u64 u[4]; float f[8]; } zu;
            const u64* src = &zmailT[((size_t)par * NWG + ow) * 256 + ub * 32 + ((uc & 63) >> 1)];
            #pragma unroll
            for (int i = 0; i < 4; ++i)
                zu.u[i] = __hip_atomic_load(src + i, __ATOMIC_RELAXED, __HIP_MEMORY_SCOPE_AGENT);
            #pragma unroll
            for (int i = 0; i < 8; ++i) zz[i] = zu.f[i];
        }
        // global LN stats (fixed ascending WG order -> identical bits in every WG)
        float S1 = 0.f, S2 = 0.f;
        #pragma unroll
        for (int i = 0; i < NWG; ++i) {
            union { u64 u; float f[2]; } pk;
            pk.u = __hip_atomic_load(&smailT[((size_t)par * NWG + i) * 8 + ub],
                                     __ATOMIC_RELAXED, __HIP_MEMORY_SCOPE_AGENT);
            S1 += pk.f[0]; S2 += pk.f[1];
        }
        const float mu  = S1 * (1.0f / SS);
        const float var = S2 * (1.0f / SS) - mu * mu;
        const float rs  = rsqrtf(var + 1e-5f);

        // replicated LN + exact GELU + h update (8 elems/thread)
        half8 hh;
        #pragma unroll
        for (int i4 = 0; i4 < 2; ++i4) {
            f32x4 gq = *(const f32x4*)&GG[uc + i4 * 4];
            f32x4 bq = *(const f32x4*)&BB[uc + i4 * 4];
            #pragma unroll
            for (int jj = 0; jj < 4; ++jj) {
                const int e = i4 * 4 + jj;
                float zn = (zz[e] - mu) * rs * gq[jj] + bq[jj];
                float ge = 0.5f * zn * (1.0f + erff(zn * 0.70710678118654752f));
                hreg[e] += ge;
                hh[e] = (_Float16)hreg[e];
            }
        }
        *(half8*)(&H16[ub][uc]) = hh;
        if (layer == 1 && ow == wg)                        // history out (feeds final GEMM)
            *(half8*)(hs1 + ((size_t)(btm + ub) * TT + t) * SS + uc) = hh;
        __syncthreads();                                   // B5
    }

    // L0 epilogue: compute + publish U1(TT-1) from the final H16, then certify with flag TT+1
    if (layer == 0) {
        if (mf) {
            f32x4 ua = {0.f, 0.f, 0.f, 0.f};
            #pragma unroll
            for (int ks = 0; ks < 16; ++ks) {
                half8 hf = *(const half8*)(&H16[r][ks * 32 + q * 8]);
                half8 ww = *(const half8*)(PW + (((size_t)(ks * 4 + q)) * SS + ccol) * 8);
                ua = __builtin_amdgcn_mfma_f32_16x16x32_f16(hf, ww, ua, 0, 0, 0);
            }
            if (q < 2) {
                u64* up = u1addr((TT - 1) & (HSLOT - 1));
                union { float f[2]; u64 u; } p0, p1;
                p0.f[0] = ua[0]; p0.f[1] = ua[1];
                p1.f[0] = ua[2]; p1.f[1] = ua[3];
                __hip_atomic_store(up + 0, p0.u, __ATOMIC_RELAXED, __HIP_MEMORY_SCOPE_AGENT);
                __hip_atomic_store(up + 1, p1.u, __ATOMIC_RELAXED, __HIP_MEMORY_SCOPE_AGENT);
            }
        }
        __builtin_amdgcn_s_waitcnt(0);
        __syncthreads();
        if (tid == 0)
            __hip_atomic_store(&flagsT[wg * 32], (unsigned)(TT + 1),
                               __ATOMIC_RELAXED, __HIP_MEMORY_SCOPE_AGENT);
    }
}

// -------------------- host launch --------------------
extern "C" void kernel_launch(void* const* d_in, const int* in_sizes, int n_in,
                              void* d_out, int out_size, void* d_ws, size_t ws_size,
                              hipStream_t stream) {
    const float* x   = (const float*)d_in[0];
    const float* A0  = (const float*)d_in[1];
    const float* B0  = (const float*)d_in[2];
    const float* C0  = (const float*)d_in[3];
    const float* K0  = (const float*)d_in[4];
    const float* ab0 = (const float*)d_in[5];
    const float* g0  = (const float*)d_in[6];
    const float* bt0 = (const float*)d_in[7];
    const float* A1  = (const float*)d_in[8];
    const float* B1  = (const float*)d_in[9];
    const float* C1  = (const float*)d_in[10];
    const float* K1  = (const float*)d_in[11];
    const float* ab1 = (const float*)d_in[12];
    const float* g1  = (const float*)d_in[13];
    const float* bt1 = (const float*)d_in[14];

    char* ws = (char*)d_ws;
    size_t off = 0;
    auto alloc = [&](size_t bytes) { size_t o = off; off = (off + bytes + 255) & ~(size_t)255; return o; };

    const size_t BUF_BYTES = (size_t)NB * TT * SS * 2;   // 33.5 MB f16
    const size_t WP_BYTES  = (size_t)SS * SS * 2;        // 512 KB f16

    _Float16* U0  = (_Float16*)(ws + alloc(BUF_BYTES));  // [t][b][c]
    _Float16* hs1 = (_Float16*)(ws + alloc(BUF_BYTES));  // [b][t][c]
    _Float16* B0T = (_Float16*)(ws + alloc(WP_BYTES));
    _Float16* C1T = (_Float16*)(ws + alloc(WP_BYTES));
    _Float16* PA0 = (_Float16*)(ws + alloc(WP_BYTES));   // packed [kk][c][8]
    _Float16* PK0 = (_Float16*)(ws + alloc(WP_BYTES));
    _Float16* PA1 = (_Float16*)(ws + alloc(WP_BYTES));
    _Float16* PK1 = (_Float16*)(ws + alloc(WP_BYTES));
    _Float16* PW  = (_Float16*)(ws + alloc(WP_BYTES));
    float*    Wf  = (float*)(ws + alloc((size_t)SS * SS * 4));
    u64*      zmail  = (u64*)(ws + alloc((size_t)4 * 2 * NWG * 256 * 8));   // 128 KB
    u64*      smail  = (u64*)(ws + alloc((size_t)4 * 2 * NWG * 8 * 8));     // 4 KB
    unsigned* flags  = (unsigned*)(ws + alloc((size_t)4 * NWG * 32 * 4));   // 4 KB
    u64*      u1mail = (u64*)(ws + alloc((size_t)NT * HSLOT * U1SLOT * 8)); // 256 KB

    // zero flags (stream-ordered; graph-replay safe)
    zinit_kernel<<<2, 512, 0, stream>>>(flags, 4 * NWG * 32);

    // weight preps
    tcvt_kernel<<<256, 256, 0, stream>>>(B0, B0T);
    tcvt_kernel<<<256, 256, 0, stream>>>(C1, C1T);
    wmm_kernel<<<512, 256, 0, stream>>>(C0, B1, Wf);     // W = C0 @ B1 (layer-fold)
    wpack_kernel<<<128, 256, 0, stream>>>(A0, PA0);
    wpack_kernel<<<128, 256, 0, stream>>>(K0, PK0);
    wpack_kernel<<<128, 256, 0, stream>>>(A1, PA1);
    wpack_kernel<<<128, 256, 0, stream>>>(K1, PK1);
    wpack_kernel<<<128, 256, 0, stream>>>(Wf, PW);

    // U0 = x @ B0, scan layout [t][b][c]
    gemm_kernel<0, 2><<<4096, 256, 0, stream>>>((const void*)x, B0T, (void*)U0);

    // fused two-layer pipelined scan: 32 WGs = {L0,L1} x {team0,team1} x 8
    scan17_kernel<<<32, 512, 0, stream>>>(U0, PA0, PK0, ab0, g0, bt0,
                                          PA1, PK1, PW, ab1, g1, bt1,
                                          hs1, zmail, smail, flags, u1mail);

    // out = hs1 @ C1 (fp32 [b][t][c])
    gemm_kernel<1, 1><<<4096, 256, 0, stream>>>((const void*)hs1, C1T, d_out);
}

// Round 21
// 12520.354 us; speedup vs baseline: 1.1735x; 1.1165x over previous
//
#include <hip/hip_runtime.h>

using half8 = __attribute__((ext_vector_type(8))) _Float16;
using f32x4 = __attribute__((ext_vector_type(4))) float;
typedef unsigned long long u64;

static constexpr int TT  = 2048;   // time steps
static constexpr int NB  = 16;     // batch
static constexpr int SS  = 512;    // state dim
static constexpr int NWG = 8;      // WGs per protocol group (64 cols each)
static constexpr int NT  = 2;      // teams (8 batches each)
static constexpr int NBT = 8;      // batches per team
static constexpr int HSLOT = 8;    // u1mail ring depth
static constexpr int U1SLOT = NWG * 4 * 2 * 16 * 2;   // 2048 u64 per team-slot

// -------------------- transpose + fp32->f16 (512x512): out[c][r] = in[r][c] --------------------
__global__ __launch_bounds__(256) void tcvt_kernel(const float* __restrict__ in,
                                                   _Float16* __restrict__ out) {
    __shared__ float tile[32][33];
    int bid = blockIdx.x;
    int rb = (bid >> 4) * 32, cb = (bid & 15) * 32;
    int tx = threadIdx.x & 31, ty = threadIdx.x >> 5;
    for (int rr = ty; rr < 32; rr += 8)
        tile[rr][tx] = in[(size_t)(rb + rr) * SS + cb + tx];
    __syncthreads();
    for (int rr = ty; rr < 32; rr += 8)
        out[(size_t)(cb + rr) * SS + rb + tx] = (_Float16)tile[tx][rr];
}

// -------------------- pack weights for scan: out[kk][c][8] f16 from fp32 [k][c] ----------------
__global__ __launch_bounds__(256) void wpack_kernel(const float* __restrict__ in,
                                                    _Float16* __restrict__ out) {
    int idx = blockIdx.x * blockDim.x + threadIdx.x;   // 64*512 = 32768
    int kk = idx >> 9, c = idx & 511;
    half8 v;
    #pragma unroll
    for (int j = 0; j < 8; ++j) v[j] = (_Float16)in[(size_t)(kk * 8 + j) * SS + c];
    *(half8*)(out + (size_t)idx * 8) = v;
}

// -------------------- W = C0 @ B1 (512x512x512 fp32) --------------------
__global__ __launch_bounds__(256) void wmm_kernel(const float* __restrict__ C0,
                                                  const float* __restrict__ B1,
                                                  float* __restrict__ W) {
    int k = blockIdx.x;
    int tid = threadIdx.x;
    const float* crow = C0 + (size_t)k * SS;
    float s0 = 0.f, s1 = 0.f;
    for (int m = 0; m < SS; ++m) {
        float cv = crow[m];
        s0 += cv * B1[(size_t)m * SS + tid];
        s1 += cv * B1[(size_t)m * SS + tid + 256];
    }
    W[(size_t)k * SS + tid] = s0;
    W[(size_t)k * SS + tid + 256] = s1;
}

// -------------------- zero flags (every launch: graph replay safe) -----------------------------
__global__ __launch_bounds__(512) void zinit_kernel(unsigned* __restrict__ p, int n) {
    int i = blockIdx.x * blockDim.x + threadIdx.x;
    if (i < n) p[i] = 0u;
}

// -------------------- big GEMM: M=32768(b*2048+t), N=512, K=512 --------------------
template <int ALAY, int MODE>
__global__ __launch_bounds__(256) void gemm_kernel(const void* __restrict__ Aptr,
                                                   const _Float16* __restrict__ BT,
                                                   void* __restrict__ Outp) {
    int lane = threadIdx.x & 63;
    int wv   = threadIdx.x >> 6;
    int wid  = blockIdx.x * 4 + wv;
    int mt   = wid >> 3;
    int nb   = (wid & 7) * 64;
    int mbase = mt * 16;
    int lo = lane & 15, q = lane >> 4;

    f32x4 acc[4] = {{0,0,0,0},{0,0,0,0},{0,0,0,0},{0,0,0,0}};

    const float*    Af = (const float*)Aptr;
    const _Float16* Ah = (const _Float16*)Aptr;
    size_t arow = (size_t)(mbase + lo) * SS;

    #pragma unroll 2
    for (int kk = 0; kk < 16; ++kk) {
        int koff = kk * 32 + q * 8;
        half8 af;
        if (ALAY == 0) {
            const float* ar = Af + arow + koff;
            f32x4 a0 = *(const f32x4*)ar;
            f32x4 a1 = *(const f32x4*)(ar + 4);
            #pragma unroll
            for (int j = 0; j < 4; ++j) { af[j] = (_Float16)a0[j]; af[4 + j] = (_Float16)a1[j]; }
        } else {
            af = *(const half8*)(Ah + arow + koff);
        }
        #pragma unroll
        for (int j = 0; j < 4; ++j) {
            int n = nb + j * 16 + lo;
            half8 bf = *(const half8*)(BT + (size_t)n * SS + koff);
            acc[j] = __builtin_amdgcn_mfma_f32_16x16x32_f16(af, bf, acc[j], 0, 0, 0);
        }
    }

    #pragma unroll
    for (int j = 0; j < 4; ++j) {
        #pragma unroll
        for (int i = 0; i < 4; ++i) {
            int m = mbase + q * 4 + i;
            int n = nb + j * 16 + lo;
            if (MODE == 0) {
                ((_Float16*)Outp)[(size_t)m * SS + n] = (_Float16)acc[j][i];
            } else if (MODE == 1) {
                ((float*)Outp)[(size_t)m * SS + n] = acc[j][i];
            } else {
                int t2 = m & (TT - 1);
                int b2 = m >> 11;                 // T = 2048 = 2^11
                ((_Float16*)Outp)[((size_t)t2 * NB + b2) * SS + n] = (_Float16)acc[j][i];
            }
        }
    }
}

// -------------------- fused two-layer pipelined cooperative scan (wave-split U1) ---------------
// L0's U1 = h(t-1) @ W matmul runs on waves 4-7 (otherwise idle in the MFMA phase), in parallel
// with waves 0-3's zA/zK on the CU's other SIMD slots. They read the shared H16 + stream PW,
// hold the result through B1, and publish to u1mail at (wg, wv&3, q, r) = consumer wave
// (wv&3)'s own coordinates. L0 waves 0-3 = 32 MFMA + 2 streams (same as L1), waves 4-7 =
// 16 MFMA + 1 stream. Protocol, thresholds, ring guard, epilogue semantics, numerics unchanged.
__global__ __launch_bounds__(512) void scan18_kernel(
        const _Float16* __restrict__ U,      // [T][NB][SS] layer-0 input proj
        const _Float16* __restrict__ PA0,    // packed f16 [kk][c][8]
        const _Float16* __restrict__ PK0,
        const float* __restrict__ ab0, const float* __restrict__ gn0, const float* __restrict__ bt0,
        const _Float16* __restrict__ PA1,
        const _Float16* __restrict__ PK1,
        const _Float16* __restrict__ PW,     // packed (C0@B1)
        const float* __restrict__ ab1, const float* __restrict__ gn1, const float* __restrict__ bt1,
        _Float16* __restrict__ hs1,          // [NB][T][SS] layer-1 history out
        u64*      __restrict__ zmail,        // [4 grp][2 par][8 wg][256] u64
        u64*      __restrict__ smail,        // [4 grp][2 par][8 wg][8] u64
        unsigned* __restrict__ flags,        // [4 grp][8 wg][32]
        u64*      __restrict__ u1mail)       // [2 team][8 slot][8 wg][4 wv][2 q][16 r][2] u64
{
    const int layer = blockIdx.x >> 4;
    const int team  = (blockIdx.x >> 3) & 1;
    const int wg    = blockIdx.x & 7;
    const int btm   = team * NBT;
    const int tid   = threadIdx.x;
    const int wv    = tid >> 6;
    const int lane  = tid & 63;
    const int q     = lane >> 4;
    const int r     = lane & 15;

    const _Float16* PA  = layer ? PA1 : PA0;
    const _Float16* PK  = layer ? PK1 : PK0;
    const float*    abp = layer ? ab1 : ab0;
    const float*    gnp = layer ? gn1 : gn0;
    const float*    btp = layer ? bt1 : bt0;

    const int pg = layer * 2 + team;
    u64*      zmailT  = zmail + (size_t)pg * (2 * NWG * 256);
    u64*      smailT  = smail + (size_t)pg * (2 * NWG * 8);
    unsigned* flagsT  = flags + (size_t)pg * (NWG * 32);
    unsigned* flagsO  = flags + (size_t)((1 - layer) * 2 + team) * (NWG * 32);
    u64*      u1mailT = u1mail + (size_t)team * HSLOT * U1SLOT;

    __shared__ _Float16 H16[16][520];          // own-layer h (rows 8-15 stay zero)
    alignas(16) __shared__ float ZW32[8][64];
    __shared__ float STAT[4][16][2];
    __shared__ float GG[512], BB[512];

    const int ub = tid & 7;             // batch within team
    const int ug = tid >> 3;            // 0..63
    const int uc = ug * 8;              // col start (8 cols/thread)
    const int ow = ug >> 3;             // owning WG of this col slice

    for (int e = tid; e < 16 * 520; e += 512) (&H16[0][0])[e] = (_Float16)0.f;
    GG[tid] = gnp[tid];
    BB[tid] = btp[tid];

    const bool mf = (wv < 4);
    const int ccol = wg * 64 + (wv & 3) * 16 + r;
    const float abreg = abp[ccol];

    // u1mail address for THIS thread's (wg, wv&3, q, r) -- producer (wv-4) and consumer (wv)
    // naturally coincide through the & 3
    auto u1addr = [&](int slot) -> u64* {
        return u1mailT + ((((size_t)slot * NWG + wg) * 4 + (wv & 3)) * 2 + q) * 32 + r * 2;
    };

    float hreg[8];
    #pragma unroll
    for (int i = 0; i < 8; ++i) hreg[i] = 0.f;
    float uprev[4] = {0.f, 0.f, 0.f, 0.f};
    float ucur[4]  = {0.f, 0.f, 0.f, 0.f};
    float unext[4] = {0.f, 0.f, 0.f, 0.f};
    float uapub[4] = {0.f, 0.f, 0.f, 0.f};
    if (layer == 0 && mf && q < 2) {
        #pragma unroll
        for (int i = 0; i < 4; ++i)
            ucur[i] = (float)U[(size_t)(btm + q * 4 + i) * SS + ccol];   // t = 0
    }
    __syncthreads();

    // L1 prologue: wait for U1(0) (computed at L0 step 1, certified by flag >= 2), gather to regs
    if (layer == 1) {
        if (wv == 0 && lane < 8) {
            while (__hip_atomic_load(&flagsO[lane * 32], __ATOMIC_RELAXED,
                                     __HIP_MEMORY_SCOPE_AGENT) < 2u) {}
        }
        __syncthreads();
        if (mf && q < 2) {
            const u64* up = u1addr(0);
            union { u64 u; float f[2]; } a, b;
            a.u = __hip_atomic_load(up + 0, __ATOMIC_RELAXED, __HIP_MEMORY_SCOPE_AGENT);
            b.u = __hip_atomic_load(up + 1, __ATOMIC_RELAXED, __HIP_MEMORY_SCOPE_AGENT);
            unext[0] = a.f[0]; unext[1] = a.f[1]; unext[2] = b.f[0]; unext[3] = b.f[1];
        }
    }

    for (int t = 0; t < TT; ++t) {
        const int par = t & 1;

        if (mf) {
            if (layer == 1) {
                #pragma unroll
                for (int i = 0; i < 4; ++i) ucur[i] = unext[i];
            }
            f32x4 zA = {0.f, 0.f, 0.f, 0.f}, zK = {0.f, 0.f, 0.f, 0.f};
            #pragma unroll
            for (int ks = 0; ks < 16; ++ks) {
                half8 hf = *(const half8*)(&H16[r][ks * 32 + q * 8]);
                half8 wa = *(const half8*)(PA + (((size_t)(ks * 4 + q)) * SS + ccol) * 8);
                half8 wk = *(const half8*)(PK + (((size_t)(ks * 4 + q)) * SS + ccol) * 8);
                zA = __builtin_amdgcn_mfma_f32_16x16x32_f16(hf, wa, zA, 0, 0, 0);
                zK = __builtin_amdgcn_mfma_f32_16x16x32_f16(hf, wk, zK, 0, 0, 0);
            }

            float z[4];
            #pragma unroll
            for (int i = 0; i < 4; ++i) {
                z[i] = zA[i] + ucur[i] + abreg + zK[i] * uprev[i];
                uprev[i] = ucur[i];
            }
            if (q < 2) {
                #pragma unroll
                for (int i = 0; i < 4; ++i)
                    ZW32[q * 4 + i][(wv & 3) * 16 + r] = z[i];
            }

            float s1[4], s2[4];
            #pragma unroll
            for (int i = 0; i < 4; ++i) { s1[i] = z[i]; s2[i] = z[i] * z[i]; }
            #pragma unroll
            for (int off = 1; off < 16; off <<= 1) {
                #pragma unroll
                for (int i = 0; i < 4; ++i) {
                    s1[i] += __shfl_xor(s1[i], off, 64);
                    s2[i] += __shfl_xor(s2[i], off, 64);
                }
            }
            if (r == 0) {
                #pragma unroll
                for (int i = 0; i < 4; ++i) {
                    STAT[wv][q * 4 + i][0] = s1[i];
                    STAT[wv][q * 4 + i][1] = s2[i];
                }
            }
        } else if (layer == 0) {
            // L0 waves 4-7 (otherwise idle here): U1(t-1) = h(t-1) @ W on the shared H16
            f32x4 ua = {0.f, 0.f, 0.f, 0.f};
            #pragma unroll
            for (int ks = 0; ks < 16; ++ks) {
                half8 hf = *(const half8*)(&H16[r][ks * 32 + q * 8]);
                half8 ww = *(const half8*)(PW + (((size_t)(ks * 4 + q)) * SS + ccol) * 8);
                ua = __builtin_amdgcn_mfma_f32_16x16x32_f16(hf, ww, ua, 0, 0, 0);
            }
            #pragma unroll
            for (int i = 0; i < 4; ++i) uapub[i] = ua[i];
        }
        __syncthreads();                                   // B1

        if (tid < 256) {
            u64 v = ((const u64*)ZW32)[tid];
            __hip_atomic_store(&zmailT[((size_t)par * NWG + wg) * 256 + tid], v,
                               __ATOMIC_RELAXED, __HIP_MEMORY_SCOPE_AGENT);
        }
        if (wv == 0 && lane < NBT) {
            float S1 = STAT[0][lane][0] + STAT[1][lane][0] + STAT[2][lane][0] + STAT[3][lane][0];
            float S2 = STAT[0][lane][1] + STAT[1][lane][1] + STAT[2][lane][1] + STAT[3][lane][1];
            union { float f[2]; u64 u; } pk;
            pk.f[0] = S1; pk.f[1] = S2;
            __hip_atomic_store(&smailT[((size_t)par * NWG + wg) * 8 + lane], pk.u,
                               __ATOMIC_RELAXED, __HIP_MEMORY_SCOPE_AGENT);
        }
        if (layer == 0 && !mf && q < 2) {
            // waves 4-7 publish U1(t-1) (ring-guard-safe: guard from step t-1 covers it)
            u64* up = u1addr((t - 1) & (HSLOT - 1));
            union { float f[2]; u64 u; } p0, p1;
            p0.f[0] = uapub[0]; p0.f[1] = uapub[1];
            p1.f[0] = uapub[2]; p1.f[1] = uapub[3];
            __hip_atomic_store(up + 0, p0.u, __ATOMIC_RELAXED, __HIP_MEMORY_SCOPE_AGENT);
            __hip_atomic_store(up + 1, p1.u, __ATOMIC_RELAXED, __HIP_MEMORY_SCOPE_AGENT);
        }
        if (layer == 0 && mf && q < 2) {
            // prefetch next-step U under the drain
            const int tn = (t + 1 < TT) ? (t + 1) : t;
            #pragma unroll
            for (int i = 0; i < 4; ++i)
                ucur[i] = (float)U[((size_t)tn * NB + btm + q * 4 + i) * SS + ccol];
        }
        __builtin_amdgcn_s_waitcnt(0);
        __syncthreads();                                   // B2: z + U1 at coherence point

        if (tid == 0)
            __hip_atomic_store(&flagsT[wg * 32], (unsigned)(t + 1),
                               __ATOMIC_RELAXED, __HIP_MEMORY_SCOPE_AGENT);
        if (wv == 0 && lane >= 1 && lane < NWG) {          // own peers
            unsigned* fp = &flagsT[((wg + lane) & (NWG - 1)) * 32];
            while (__hip_atomic_load(fp, __ATOMIC_RELAXED, __HIP_MEMORY_SCOPE_AGENT)
                   < (unsigned)(t + 1)) {}
        }
        if (wv == 0 && lane >= 8 && lane < 16) {           // cross-layer
            unsigned thr;
            if (layer == 0) thr = (t > 7) ? (unsigned)(t - 7) : 0u;      // ring overwrite guard
            else            thr = (t + 1 < TT) ? (unsigned)(t + 3) : 0u; // U1(t+1) certified
            if (thr) {
                unsigned* fp = &flagsO[(lane - 8) * 32];
                while (__hip_atomic_load(fp, __ATOMIC_RELAXED, __HIP_MEMORY_SCOPE_AGENT) < thr) {}
            }
        }
        __syncthreads();                                   // B3

        // L1: gather U1(t+1) straight into registers (shares the RT window with z/stats gathers)
        if (layer == 1 && mf && q < 2 && t + 1 < TT) {
            const u64* up = u1addr((t + 1) & (HSLOT - 1));
            union { u64 u; float f[2]; } a, b;
            a.u = __hip_atomic_load(up + 0, __ATOMIC_RELAXED, __HIP_MEMORY_SCOPE_AGENT);
            b.u = __hip_atomic_load(up + 1, __ATOMIC_RELAXED, __HIP_MEMORY_SCOPE_AGENT);
            unext[0] = a.f[0]; unext[1] = a.f[1]; unext[2] = b.f[0]; unext[3] = b.f[1];
        }

        // gather z (batch ub, cols uc..uc+7)
        float zz[8];
        if (ow == wg) {
            #pragma unroll
            for (int i = 0; i < 8; ++i) zz[i] = ZW32[ub][(uc & 63) + i];
        } else {
            union { u64 u[4]; float f[8]; } zu;
            const u64* src = &zmailT[((size_t)par * NWG + ow) * 256 + ub * 32 + ((uc & 63) >> 1)];
            #pragma unroll
            for (int i = 0; i < 4; ++i)
                zu.u[i] = __hip_atomic_load(src + i, __ATOMIC_RELAXED, __HIP_MEMORY_SCOPE_AGENT);
            #pragma unroll
            for (int i = 0; i < 8; ++i) zz[i] = zu.f[i];
        }
        // global LN stats (fixed ascending WG order -> identical bits in every WG)
        float S1 = 0.f, S2 = 0.f;
        #pragma unroll
        for (int i = 0; i < NWG; ++i) {
            union { u64 u; float f[2]; } pk;
            pk.u = __hip_atomic_load(&smailT[((size_t)par * NWG + i) * 8 + ub],
                                     __ATOMIC_RELAXED, __HIP_MEMORY_SCOPE_AGENT);
            S1 += pk.f[0]; S2 += pk.f[1];
        }
        const float mu  = S1 * (1.0f / SS);
        const float var = S2 * (1.0f / SS) - mu * mu;
        const float rs  = rsqrtf(var + 1e-5f);

        // replicated LN + exact GELU + h update (8 elems/thread)
        half8 hh;
        #pragma unroll
        for (int i4 = 0; i4 < 2; ++i4) {
            f32x4 gq = *(const f32x4*)&GG[uc + i4 * 4];
            f32x4 bq = *(const f32x4*)&BB[uc + i4 * 4];
            #pragma unroll
            for (int jj = 0; jj < 4; ++jj) {
                const int e = i4 * 4 + jj;
                float zn = (zz[e] - mu) * rs * gq[jj] + bq[jj];
                float ge = 0.5f * zn * (1.0f + erff(zn * 0.70710678118654752f));
                hreg[e] += ge;
                hh[e] = (_Float16)hreg[e];
            }
        }
        *(half8*)(&H16[ub][uc]) = hh;
        if (layer == 1 && ow == wg)                        // history out (feeds final GEMM)
            *(half8*)(hs1 + ((size_t)(btm + ub) * TT + t) * SS + uc) = hh;
        __syncthreads();                                   // B5
    }

    // L0 epilogue: waves 4-7 compute + publish U1(TT-1) from the final H16, then flag TT+1
    if (layer == 0) {
        if (!mf) {
            f32x4 ua = {0.f, 0.f, 0.f, 0.f};
            #pragma unroll
            for (int ks = 0; ks < 16; ++ks) {
                half8 hf = *(const half8*)(&H16[r][ks * 32 + q * 8]);
                half8 ww = *(const half8*)(PW + (((size_t)(ks * 4 + q)) * SS + ccol) * 8);
                ua = __builtin_amdgcn_mfma_f32_16x16x32_f16(hf, ww, ua, 0, 0, 0);
            }
            if (q < 2) {
                u64* up = u1addr((TT - 1) & (HSLOT - 1));
                union { float f[2]; u64 u; } p0, p1;
                p0.f[0] = ua[0]; p0.f[1] = ua[1];
                p1.f[0] = ua[2]; p1.f[1] = ua[3];
                __hip_atomic_store(up + 0, p0.u, __ATOMIC_RELAXED, __HIP_MEMORY_SCOPE_AGENT);
                __hip_atomic_store(up + 1, p1.u, __ATOMIC_RELAXED, __HIP_MEMORY_SCOPE_AGENT);
            }
        }
        __builtin_amdgcn_s_waitcnt(0);
        __syncthreads();
        if (tid == 0)
            __hip_atomic_store(&flagsT[wg * 32], (unsigned)(TT + 1),
                               __ATOMIC_RELAXED, __HIP_MEMORY_SCOPE_AGENT);
    }
}

// -------------------- host launch --------------------
extern "C" void kernel_launch(void* const* d_in, const int* in_sizes, int n_in,
                              void* d_out, int out_size, void* d_ws, size_t ws_size,
                              hipStream_t stream) {
    const float* x   = (const float*)d_in[0];
    const float* A0  = (const float*)d_in[1];
    const float* B0  = (const float*)d_in[2];
    const float* C0  = (const float*)d_in[3];
    const float* K0  = (const float*)d_in[4];
    const float* ab0 = (const float*)d_in[5];
    const float* g0  = (const float*)d_in[6];
    const float* bt0 = (const float*)d_in[7];
    const float* A1  = (const float*)d_in[8];
    const float* B1  = (const float*)d_in[9];
    const float* C1  = (const float*)d_in[10];
    const float* K1  = (const float*)d_in[11];
    const float* ab1 = (const float*)d_in[12];
    const float* g1  = (const float*)d_in[13];
    const float* bt1 = (const float*)d_in[14];

    char* ws = (char*)d_ws;
    size_t off = 0;
    auto alloc = [&](size_t bytes) { size_t o = off; off = (off + bytes + 255) & ~(size_t)255; return o; };

    const size_t BUF_BYTES = (size_t)NB * TT * SS * 2;   // 33.5 MB f16
    const size_t WP_BYTES  = (size_t)SS * SS * 2;        // 512 KB f16

    _Float16* U0  = (_Float16*)(ws + alloc(BUF_BYTES));  // [t][b][c]
    _Float16* hs1 = (_Float16*)(ws + alloc(BUF_BYTES));  // [b][t][c]
    _Float16* B0T = (_Float16*)(ws + alloc(WP_BYTES));
    _Float16* C1T = (_Float16*)(ws + alloc(WP_BYTES));
    _Float16* PA0 = (_Float16*)(ws + alloc(WP_BYTES));   // packed [kk][c][8]
    _Float16* PK0 = (_Float16*)(ws + alloc(WP_BYTES));
    _Float16* PA1 = (_Float16*)(ws + alloc(WP_BYTES));
    _Float16* PK1 = (_Float16*)(ws + alloc(WP_BYTES));
    _Float16* PW  = (_Float16*)(ws + alloc(WP_BYTES));
    float*    Wf  = (float*)(ws + alloc((size_t)SS * SS * 4));
    u64*      zmail  = (u64*)(ws + alloc((size_t)4 * 2 * NWG * 256 * 8));   // 128 KB
    u64*      smail  = (u64*)(ws + alloc((size_t)4 * 2 * NWG * 8 * 8));     // 4 KB
    unsigned* flags  = (unsigned*)(ws + alloc((size_t)4 * NWG * 32 * 4));   // 4 KB
    u64*      u1mail = (u64*)(ws + alloc((size_t)NT * HSLOT * U1SLOT * 8)); // 256 KB

    // zero flags (stream-ordered; graph-replay safe)
    zinit_kernel<<<2, 512, 0, stream>>>(flags, 4 * NWG * 32);

    // weight preps
    tcvt_kernel<<<256, 256, 0, stream>>>(B0, B0T);
    tcvt_kernel<<<256, 256, 0, stream>>>(C1, C1T);
    wmm_kernel<<<512, 256, 0, stream>>>(C0, B1, Wf);     // W = C0 @ B1 (layer-fold)
    wpack_kernel<<<128, 256, 0, stream>>>(A0, PA0);
    wpack_kernel<<<128, 256, 0, stream>>>(K0, PK0);
    wpack_kernel<<<128, 256, 0, stream>>>(A1, PA1);
    wpack_kernel<<<128, 256, 0, stream>>>(K1, PK1);
    wpack_kernel<<<128, 256, 0, stream>>>(Wf, PW);

    // U0 = x @ B0, scan layout [t][b][c]
    gemm_kernel<0, 2><<<4096, 256, 0, stream>>>((const void*)x, B0T, (void*)U0);

    // fused two-layer pipelined scan: 32 WGs = {L0,L1} x {team0,team1} x 8
    scan18_kernel<<<32, 512, 0, stream>>>(U0, PA0, PK0, ab0, g0, bt0,
                                          PA1, PK1, PW, ab1, g1, bt1,
                                          hs1, zmail, smail, flags, u1mail);

    // out = hs1 @ C1 (fp32 [b][t][c])
    gemm_kernel<1, 1><<<4096, 256, 0, stream>>>((const void*)hs1, C1T, d_out);
}